// Round 1
// baseline (182.610 us; speedup 1.0000x reference)
//
#include <hip/hip_runtime.h>
#include <math.h>

// ---------------- problem constants ----------------
#define NB 8          // batch
#define NM 16         // modes
#define NPH 8         // photons
#define NSTATES 12870 // C(16,8)
#define NSUB 256      // 2^NPH column subsets
#define OUTS 128
#define NTILES 824    // sum over classes of ceil(R/4)*ceil(C/4)
#define NSLOTS (NTILES*16) // 13184
#define NSGQ 8        // s-groups of 32 (partial-accumulation granularity)
#define SPH 16        // s per LDS phase (2 phases per s-group)
#define NTG 4         // tile groups
#define TILES_PER_TG 206
#define KCH 101       // k-chunk for output gemm

// ---------------- compile-time tables ----------------
struct Tables {
  int binom[17][9];
  unsigned char cls_masks[256]; // 8-bit masks sorted by (popcount, value)
  int cls_off[10];              // offsets into cls_masks per popcount
  int nt1[9], nt2[9];           // 4-tiles per dim per class
  int tile_off[10];
};

constexpr int cpopc(int x){ int c=0; while(x){ c += x & 1; x >>= 1; } return c; }

constexpr Tables make_tables(){
  Tables t{};
  for (int n=0;n<=16;n++)
    for (int k=0;k<=8;k++){
      if (k==0) t.binom[n][k]=1;
      else if (n==0) t.binom[n][k]=0;
      else t.binom[n][k]=t.binom[n-1][k-1]+t.binom[n-1][k];
    }
  int idx=0;
  for (int p=0;p<=8;p++){
    t.cls_off[p]=idx;
    for (int m=0;m<256;m++) if (cpopc(m)==p) t.cls_masks[idx++]=(unsigned char)m;
  }
  t.cls_off[9]=idx; // 256
  int toff=0;
  for (int c=0;c<=8;c++){
    int R=t.binom[8][c], C=t.binom[8][8-c];
    t.nt1[c]=(R+3)/4; t.nt2[c]=(C+3)/4;
    t.tile_off[c]=toff; toff += t.nt1[c]*t.nt2[c];
  }
  t.tile_off[9]=toff;
  return t;
}

constexpr Tables HTBL = make_tables();
static_assert(HTBL.tile_off[9]==NTILES, "tile count");
static_assert(HTBL.cls_off[9]==256, "mask count");
__device__ const Tables TBL = HTBL;

// next-pow2 shift for masks-per-level: C(8,p) = 1,8,28,56,70,56,28,8,1
__device__ const int LVL_SHIFT[9] = {0,3,5,6,7,6,5,3,0};

// ---------------- workspace layout (bytes) ----------------
#define WS_SUMS   0                        // 8 floats (memset 0)
#define WS_V      256                      // [NB][NSUB][NM] float2 = 262144 B
#define WS_TMAP   262400                   // NSLOTS ints = 52736 B (memset 0xFF)
#define WS_PROBS  315136                   // [NB][NSTATES] float = 411840 B
#define WS_PART   727040                   // [NB][NSGQ][NSLOTS] float2 = 6750208 B
#define TMAP_BYTES (NSLOTS*4)

// ---------------- complex helpers ----------------
__device__ __forceinline__ float2 cmul(float2 a, float2 b){
  return make_float2(fmaf(a.x,b.x,-(a.y*b.y)), fmaf(a.x,b.y, a.y*b.x));
}
__device__ __forceinline__ void cmac(float2& acc, float2 a, float2 b){
  acc.x = fmaf(a.x, b.x, acc.x); acc.x = fmaf(-a.y, b.y, acc.x);
  acc.y = fmaf(a.x, b.y, acc.y); acc.y = fmaf(a.y, b.x, acc.y);
}

// ---------------- K1: unitaries + V table + tile map ----------------
__global__ __launch_bounds__(256) void k_setup(
    const float* __restrict__ x, const float* __restrict__ th1,
    const float* __restrict__ th2, const float* __restrict__ mr,
    const float* __restrict__ mi, const int* __restrict__ rows, char* ws)
{
  int tid = threadIdx.x;
  if (blockIdx.x < NB) {
    int b = blockIdx.x;
    __shared__ float2 T1[NM][NM], T2[NM][NM], Am[NM][NM], Bm[NM][NM];
    __shared__ float2 EA[NM][NPH], Uin[NM][NPH], ex[NM];
    int r = tid >> 4, cc = tid & 15;
    {
      float sn, cs;
      sincosf(th1[r], &sn, &cs);
      float a = mr[0*256 + tid], bb = mi[0*256 + tid];   // M0[r][cc]
      T1[r][cc] = make_float2(cs*a - sn*bb, cs*bb + sn*a);
      sincosf(th2[r], &sn, &cs);
      float a2 = mr[2*256 + tid], b2 = mi[2*256 + tid];  // M2[r][cc]
      T2[r][cc] = make_float2(cs*a2 - sn*b2, cs*b2 + sn*a2);
    }
    __syncthreads();
    {
      float2 accA = make_float2(0,0), accB = make_float2(0,0);
      for (int m=0;m<NM;m++){
        float2 m1 = make_float2(mr[1*256 + r*16+m], mi[1*256 + r*16+m]);
        cmac(accA, m1, T1[m][cc]);
        float2 m3 = make_float2(mr[3*256 + r*16+m], mi[3*256 + r*16+m]);
        cmac(accB, m3, T2[m][cc]);
      }
      Am[r][cc] = accA; Bm[r][cc] = accB;
    }
    if (tid < NM){ float sn,cs; sincosf(x[b*NM+tid], &sn, &cs); ex[tid] = make_float2(cs, sn); }
    __syncthreads();
    if (tid < NM*NPH){ int m = tid >> 3, n = tid & 7; EA[m][n] = cmul(ex[m], Am[m][n]); }
    __syncthreads();
    if (tid < NM*NPH){
      int p = tid >> 3, n = tid & 7;
      float2 acc = make_float2(0,0);
      for (int m=0;m<NM;m++) cmac(acc, Bm[p][m], EA[m][n]);
      Uin[p][n] = acc;
    }
    __syncthreads();
    // V[s][m] = sum over set bits j of s of Uin[m][j];  thread tid == s
    float2* Vg = (float2*)(ws + WS_V);
    int s = tid;
    for (int m=0;m<NM;m++){
      float2 acc = make_float2(0,0);
      #pragma unroll
      for (int j=0;j<NPH;j++)
        if ((s>>j) & 1){ acc.x += Uin[m][j].x; acc.y += Uin[m][j].y; }
      Vg[b*(NSUB*NM) + s*NM + m] = acc;
    }
  } else {
    // tile map: state k -> (tile, slot)
    int k = (blockIdx.x - NB)*256 + tid;
    if (k < NSTATES){
      int t1=0, t2=0;
      #pragma unroll
      for (int i=0;i<NPH;i++){
        int rr = rows[k*NPH+i];
        if (rr < 8) t1 |= 1 << rr; else t2 |= 1 << (rr-8);
      }
      int c1 = __popc(t1);
      int rk1=0, cnt=0;
      #pragma unroll
      for (int bb=0;bb<8;bb++) if ((t1>>bb)&1){ cnt++; rk1 += TBL.binom[bb][cnt]; }
      int rk2=0; cnt=0;
      #pragma unroll
      for (int bb=0;bb<8;bb++) if ((t2>>bb)&1){ cnt++; rk2 += TBL.binom[bb][cnt]; }
      int tile = TBL.tile_off[c1] + (rk1>>2)*TBL.nt2[c1] + (rk2>>2);
      int slot = ((rk1&3)<<2) | (rk2&3);
      ((int*)(ws + WS_TMAP))[tile*16 + slot] = k;
    }
  }
}

// ---------------- K2: factorized Ryser main ----------------
__global__ __launch_bounds__(256) void k_main(char* ws)
{
  __shared__ float2 P1L[SPH][256];   // 32 KB
  __shared__ float2 P2L[SPH][256];   // 32 KB  (total exactly 64 KB)
  const float2* __restrict__ Vg = (const float2*)(ws + WS_V);
  float2* __restrict__ part = (float2*)(ws + WS_PART);
  int tid = threadIdx.x;
  int blk = blockIdx.x;
  int b = blk >> 5, rest = blk & 31, sgq = rest >> 2, tg = rest & 3;
  bool active = tid < TILES_PER_TG;
  int tile = tg + 4*tid;
  int t1v[4] = {0,0,0,0}, t2v[4] = {0,0,0,0};
  if (active){
    int c = 0;
    while (tile >= TBL.tile_off[c+1]) c++;
    int local = tile - TBL.tile_off[c];
    int n2 = TBL.nt2[c];
    int ti = local / n2, tj = local - ti*n2;
    int R = TBL.binom[8][c], C2 = TBL.binom[8][8-c];
    #pragma unroll
    for (int i=0;i<4;i++){ int r1 = ti*4+i; t1v[i] = (r1<R) ? (int)TBL.cls_masks[TBL.cls_off[c]+r1] : 0; }
    #pragma unroll
    for (int j=0;j<4;j++){ int r2 = tj*4+j; t2v[j] = (r2<C2) ? (int)TBL.cls_masks[TBL.cls_off[8-c]+r2] : 0; }
  }
  float2 acc[4][4] = {};
  for (int ph=0; ph<2; ph++){
    int sbase = sgq*32 + ph*SPH;
    // level-0 init (sign of Ryser folded into P1)
    if (tid < 2*SPH){
      int table = tid >> 4, s = tid & 15;
      float sg = 1.0f;
      if (table==0 && (__popc(sbase+s) & 1)) sg = -1.0f;
      (table ? P2L : P1L)[s][0] = make_float2(sg, 0.0f);
    }
    __syncthreads();
    // DP build: P[t] = P[t & (t-1)] * V[row(lowbit)]
    for (int p=1;p<=8;p++){
      int nm = TBL.cls_off[p+1]-TBL.cls_off[p];
      int sh = LVL_SHIFT[p];
      int tot = (2*SPH) << sh;
      for (int q=tid; q<tot; q+=256){
        int mi2 = q & ((1<<sh)-1);
        if (mi2 < nm){
          int ts = q >> sh; int s = ts & 15, table = ts >> 4;
          int t = (int)TBL.cls_masks[TBL.cls_off[p]+mi2];
          int par = t & (t-1);
          int row = (__ffs(t)-1) + table*8;
          float2 pv = (table ? P2L : P1L)[s][par];
          float2 vv = Vg[b*(NSUB*NM) + (sbase+s)*NM + row];
          (table ? P2L : P1L)[s][t] = cmul(pv, vv);
        }
      }
      __syncthreads();
    }
    // 4x4 register-tiled combine
    if (active){
      for (int s=0;s<SPH;s++){
        float2 av[4], bv[4];
        #pragma unroll
        for (int i=0;i<4;i++) av[i] = P1L[s][t1v[i]];
        #pragma unroll
        for (int j=0;j<4;j++) bv[j] = P2L[s][t2v[j]];
        #pragma unroll
        for (int i=0;i<4;i++)
          #pragma unroll
          for (int j=0;j<4;j++) cmac(acc[i][j], av[i], bv[j]);
      }
    }
    __syncthreads();
  }
  if (active){
    float2* dst = part + (size_t)(b*NSGQ + sgq)*NSLOTS + (size_t)tile*16;
    #pragma unroll
    for (int i=0;i<4;i++)
      #pragma unroll
      for (int j=0;j<4;j++) dst[i*4+j] = acc[i][j];
  }
}

// ---------------- K3: reduce partials -> probs + batch sums ----------------
__global__ __launch_bounds__(256) void k_reduce(char* ws)
{
  int slot = blockIdx.x*256 + threadIdx.x;
  const int* __restrict__ tmap = (const int*)(ws + WS_TMAP);
  const float2* __restrict__ part = (const float2*)(ws + WS_PART);
  float* __restrict__ probs = (float*)(ws + WS_PROBS);
  float* __restrict__ sums = (float*)(ws + WS_SUMS);
  int k = (slot < NSLOTS) ? tmap[slot] : -1;
  float bsum[NB];
  #pragma unroll
  for (int b=0;b<NB;b++){
    float pr = 0.0f;
    if (k >= 0){
      float2 amp = make_float2(0,0);
      #pragma unroll
      for (int sgq=0;sgq<NSGQ;sgq++){
        float2 v = part[(size_t)(b*NSGQ+sgq)*NSLOTS + slot];
        amp.x += v.x; amp.y += v.y;
      }
      pr = fmaf(amp.x, amp.x, amp.y*amp.y);
      probs[b*NSTATES + k] = pr;
    }
    bsum[b] = pr;
  }
  #pragma unroll
  for (int b=0;b<NB;b++){
    float v = bsum[b];
    for (int off=32; off>0; off>>=1) v += __shfl_down(v, off);
    if ((threadIdx.x & 63) == 0) atomicAdd(&sums[b], v);
  }
}

// ---------------- K4: out = probs_norm @ weight + bias ----------------
__global__ __launch_bounds__(128) void k_out(
    const float* __restrict__ wgt, const float* __restrict__ bias,
    const char* __restrict__ ws, float* __restrict__ out)
{
  const float* __restrict__ probs = (const float*)(ws + WS_PROBS);
  const float* __restrict__ sums = (const float*)(ws + WS_SUMS);
  int o = threadIdx.x;
  int kb = blockIdx.x * KCH;
  int ke = min(NSTATES, kb + KCH);
  float acc[NB] = {0,0,0,0,0,0,0,0};
  for (int k=kb;k<ke;k++){
    float w = wgt[k*OUTS + o];
    #pragma unroll
    for (int b=0;b<NB;b++) acc[b] = fmaf(probs[b*NSTATES+k], w, acc[b]);
  }
  #pragma unroll
  for (int b=0;b<NB;b++){
    float r = acc[b] / sums[b];
    if (blockIdx.x == 0) r += bias[o];
    atomicAdd(&out[b*OUTS+o], r);
  }
}

// ---------------- launch ----------------
extern "C" void kernel_launch(void* const* d_in, const int* in_sizes, int n_in,
                              void* d_out, int out_size, void* d_ws, size_t ws_size,
                              hipStream_t stream) {
  const float* x    = (const float*)d_in[0];
  const float* th1  = (const float*)d_in[1];
  const float* th2  = (const float*)d_in[2];
  const float* mr   = (const float*)d_in[3];
  const float* mi   = (const float*)d_in[4];
  const float* wgt  = (const float*)d_in[5];
  const float* bias = (const float*)d_in[6];
  const int*   rows = (const int*)d_in[7];
  float* out = (float*)d_out;
  char* ws = (char*)d_ws;

  hipMemsetAsync(ws + WS_SUMS, 0, 32, stream);
  hipMemsetAsync(ws + WS_TMAP, 0xFF, TMAP_BYTES, stream);
  hipMemsetAsync(d_out, 0, (size_t)out_size * sizeof(float), stream);

  k_setup<<<NB + (NSTATES + 255)/256, 256, 0, stream>>>(x, th1, th2, mr, mi, rows, ws);
  k_main<<<NB*NSGQ*NTG, 256, 0, stream>>>(ws);
  k_reduce<<<(NSLOTS + 255)/256, 256, 0, stream>>>(ws);
  k_out<<<(NSTATES + KCH - 1)/KCH, 128, 0, stream>>>(wgt, bias, ws, out);
}

// Round 2
// 182.421 us; speedup vs baseline: 1.0010x; 1.0010x over previous
//
#include <hip/hip_runtime.h>
#include <math.h>

// ---------------- problem constants ----------------
#define NB 8          // batch
#define NM 16         // modes
#define NPH 8         // photons
#define NSTATES 12870 // C(16,8)
#define NSUB 256      // 2^NPH column subsets
#define OUTS 128
#define NTILES 824    // sum over classes of ceil(R/4)*ceil(C/4)
#define NSLOTS (NTILES*16) // 13184
#define NSGQ 8        // s-groups of 32 (partial-accumulation granularity)
#define SPH 16        // s per LDS phase (2 phases per s-group)
#define NTG 4         // tile groups
#define TILES_PER_TG 206
#define KS2 32        // k-rows per block in output gemm
#define NSPLIT ((NSTATES + KS2 - 1)/KS2)  // 403

// ---------------- compile-time tables ----------------
struct Tables {
  int binom[17][9];
  unsigned char cls_masks[256]; // 8-bit masks sorted by (popcount, value)
  int cls_off[10];              // offsets into cls_masks per popcount
  int nt1[9], nt2[9];           // 4-tiles per dim per class
  int tile_off[10];
};

constexpr int cpopc(int x){ int c=0; while(x){ c += x & 1; x >>= 1; } return c; }

constexpr Tables make_tables(){
  Tables t{};
  for (int n=0;n<=16;n++)
    for (int k=0;k<=8;k++){
      if (k==0) t.binom[n][k]=1;
      else if (n==0) t.binom[n][k]=0;
      else t.binom[n][k]=t.binom[n-1][k-1]+t.binom[n-1][k];
    }
  int idx=0;
  for (int p=0;p<=8;p++){
    t.cls_off[p]=idx;
    for (int m=0;m<256;m++) if (cpopc(m)==p) t.cls_masks[idx++]=(unsigned char)m;
  }
  t.cls_off[9]=idx; // 256
  int toff=0;
  for (int c=0;c<=8;c++){
    int R=t.binom[8][c], C=t.binom[8][8-c];
    t.nt1[c]=(R+3)/4; t.nt2[c]=(C+3)/4;
    t.tile_off[c]=toff; toff += t.nt1[c]*t.nt2[c];
  }
  t.tile_off[9]=toff;
  return t;
}

constexpr Tables HTBL = make_tables();
static_assert(HTBL.tile_off[9]==NTILES, "tile count");
static_assert(HTBL.cls_off[9]==256, "mask count");
__device__ const Tables TBL = HTBL;

// next-pow2 shift for masks-per-level: C(8,p) = 1,8,28,56,70,56,28,8,1
__device__ const int LVL_SHIFT[9] = {0,3,5,6,7,6,5,3,0};

// ---------------- workspace layout (bytes) ----------------
#define WS_SUMS   0                        // 8 floats (memset 0)
#define WS_V      256                      // [NB][NSUB][NM] float2 = 262144 B
#define WS_TMAP   262400                   // NSLOTS ints = 52736 B (memset 0xFF)
#define WS_PROBS  315136                   // [NB][NSTATES] float = 411840 B
#define WS_PART   727040                   // [NB][NSGQ][NSLOTS] float2 = 6750208 B
#define TMAP_BYTES (NSLOTS*4)

// ---------------- complex helpers ----------------
__device__ __forceinline__ float2 cmul(float2 a, float2 b){
  return make_float2(fmaf(a.x,b.x,-(a.y*b.y)), fmaf(a.x,b.y, a.y*b.x));
}
__device__ __forceinline__ void cmac(float2& acc, float2 a, float2 b){
  acc.x = fmaf(a.x, b.x, acc.x); acc.x = fmaf(-a.y, b.y, acc.x);
  acc.y = fmaf(a.x, b.y, acc.y); acc.y = fmaf(a.y, b.x, acc.y);
}

// ---------------- K1: unitaries + V table + tile map ----------------
__global__ __launch_bounds__(256) void k_setup(
    const float* __restrict__ x, const float* __restrict__ th1,
    const float* __restrict__ th2, const float* __restrict__ mr,
    const float* __restrict__ mi, const int* __restrict__ rows, char* ws)
{
  int tid = threadIdx.x;
  if (blockIdx.x < NB) {
    int b = blockIdx.x;
    __shared__ float2 T1[NM][NM], T2[NM][NM], Am[NM][NM], Bm[NM][NM];
    __shared__ float2 EA[NM][NPH], Uin[NM][NPH], ex[NM];
    int r = tid >> 4, cc = tid & 15;
    {
      float sn, cs;
      sincosf(th1[r], &sn, &cs);
      float a = mr[0*256 + tid], bb = mi[0*256 + tid];   // M0[r][cc]
      T1[r][cc] = make_float2(cs*a - sn*bb, cs*bb + sn*a);
      sincosf(th2[r], &sn, &cs);
      float a2 = mr[2*256 + tid], b2 = mi[2*256 + tid];  // M2[r][cc]
      T2[r][cc] = make_float2(cs*a2 - sn*b2, cs*b2 + sn*a2);
    }
    __syncthreads();
    {
      float2 accA = make_float2(0,0), accB = make_float2(0,0);
      for (int m=0;m<NM;m++){
        float2 m1 = make_float2(mr[1*256 + r*16+m], mi[1*256 + r*16+m]);
        cmac(accA, m1, T1[m][cc]);
        float2 m3 = make_float2(mr[3*256 + r*16+m], mi[3*256 + r*16+m]);
        cmac(accB, m3, T2[m][cc]);
      }
      Am[r][cc] = accA; Bm[r][cc] = accB;
    }
    if (tid < NM){ float sn,cs; sincosf(x[b*NM+tid], &sn, &cs); ex[tid] = make_float2(cs, sn); }
    __syncthreads();
    if (tid < NM*NPH){ int m = tid >> 3, n = tid & 7; EA[m][n] = cmul(ex[m], Am[m][n]); }
    __syncthreads();
    if (tid < NM*NPH){
      int p = tid >> 3, n = tid & 7;
      float2 acc = make_float2(0,0);
      for (int m=0;m<NM;m++) cmac(acc, Bm[p][m], EA[m][n]);
      Uin[p][n] = acc;
    }
    __syncthreads();
    // V[s][m] = sum over set bits j of s of Uin[m][j];  thread tid == s
    float2* Vg = (float2*)(ws + WS_V);
    int s = tid;
    for (int m=0;m<NM;m++){
      float2 acc = make_float2(0,0);
      #pragma unroll
      for (int j=0;j<NPH;j++)
        if ((s>>j) & 1){ acc.x += Uin[m][j].x; acc.y += Uin[m][j].y; }
      Vg[b*(NSUB*NM) + s*NM + m] = acc;
    }
  } else {
    // tile map: state k -> (tile, slot)
    int k = (blockIdx.x - NB)*256 + tid;
    if (k < NSTATES){
      int t1=0, t2=0;
      #pragma unroll
      for (int i=0;i<NPH;i++){
        int rr = rows[k*NPH+i];
        if (rr < 8) t1 |= 1 << rr; else t2 |= 1 << (rr-8);
      }
      int c1 = __popc(t1);
      int rk1=0, cnt=0;
      #pragma unroll
      for (int bb=0;bb<8;bb++) if ((t1>>bb)&1){ cnt++; rk1 += TBL.binom[bb][cnt]; }
      int rk2=0; cnt=0;
      #pragma unroll
      for (int bb=0;bb<8;bb++) if ((t2>>bb)&1){ cnt++; rk2 += TBL.binom[bb][cnt]; }
      int tile = TBL.tile_off[c1] + (rk1>>2)*TBL.nt2[c1] + (rk2>>2);
      int slot = ((rk1&3)<<2) | (rk2&3);
      ((int*)(ws + WS_TMAP))[tile*16 + slot] = k;
    }
  }
}

// ---------------- K2: factorized Ryser main ----------------
__global__ __launch_bounds__(256) void k_main(char* ws)
{
  __shared__ float2 P1L[SPH][256];   // 32 KB
  __shared__ float2 P2L[SPH][256];   // 32 KB  (total exactly 64 KB)
  const float2* __restrict__ Vg = (const float2*)(ws + WS_V);
  float2* __restrict__ part = (float2*)(ws + WS_PART);
  int tid = threadIdx.x;
  int blk = blockIdx.x;
  int b = blk >> 5, rest = blk & 31, sgq = rest >> 2, tg = rest & 3;
  bool active = tid < TILES_PER_TG;
  int tile = tg + 4*tid;
  int t1v[4] = {0,0,0,0}, t2v[4] = {0,0,0,0};
  if (active){
    int c = 0;
    while (tile >= TBL.tile_off[c+1]) c++;
    int local = tile - TBL.tile_off[c];
    int n2 = TBL.nt2[c];
    int ti = local / n2, tj = local - ti*n2;
    int R = TBL.binom[8][c], C2 = TBL.binom[8][8-c];
    #pragma unroll
    for (int i=0;i<4;i++){ int r1 = ti*4+i; t1v[i] = (r1<R) ? (int)TBL.cls_masks[TBL.cls_off[c]+r1] : 0; }
    #pragma unroll
    for (int j=0;j<4;j++){ int r2 = tj*4+j; t2v[j] = (r2<C2) ? (int)TBL.cls_masks[TBL.cls_off[8-c]+r2] : 0; }
  }
  float2 acc[4][4] = {};
  for (int ph=0; ph<2; ph++){
    int sbase = sgq*32 + ph*SPH;
    // level-0 init (sign of Ryser folded into P1)
    if (tid < 2*SPH){
      int table = tid >> 4, s = tid & 15;
      float sg = 1.0f;
      if (table==0 && (__popc(sbase+s) & 1)) sg = -1.0f;
      (table ? P2L : P1L)[s][0] = make_float2(sg, 0.0f);
    }
    __syncthreads();
    // DP build: P[t] = P[t & (t-1)] * V[row(lowbit)]
    for (int p=1;p<=8;p++){
      int nm = TBL.cls_off[p+1]-TBL.cls_off[p];
      int sh = LVL_SHIFT[p];
      int tot = (2*SPH) << sh;
      for (int q=tid; q<tot; q+=256){
        int mi2 = q & ((1<<sh)-1);
        if (mi2 < nm){
          int ts = q >> sh; int s = ts & 15, table = ts >> 4;
          int t = (int)TBL.cls_masks[TBL.cls_off[p]+mi2];
          int par = t & (t-1);
          int row = (__ffs(t)-1) + table*8;
          float2 pv = (table ? P2L : P1L)[s][par];
          float2 vv = Vg[b*(NSUB*NM) + (sbase+s)*NM + row];
          (table ? P2L : P1L)[s][t] = cmul(pv, vv);
        }
      }
      __syncthreads();
    }
    // 4x4 register-tiled combine
    if (active){
      for (int s=0;s<SPH;s++){
        float2 av[4], bv[4];
        #pragma unroll
        for (int i=0;i<4;i++) av[i] = P1L[s][t1v[i]];
        #pragma unroll
        for (int j=0;j<4;j++) bv[j] = P2L[s][t2v[j]];
        #pragma unroll
        for (int i=0;i<4;i++)
          #pragma unroll
          for (int j=0;j<4;j++) cmac(acc[i][j], av[i], bv[j]);
      }
    }
    __syncthreads();
  }
  if (active){
    float2* dst = part + (size_t)(b*NSGQ + sgq)*NSLOTS + (size_t)tile*16;
    #pragma unroll
    for (int i=0;i<4;i++)
      #pragma unroll
      for (int j=0;j<4;j++) dst[i*4+j] = acc[i][j];
  }
}

// ---------------- K3: reduce partials -> probs + batch sums ----------------
__global__ __launch_bounds__(256) void k_reduce(char* ws)
{
  int slot = blockIdx.x*256 + threadIdx.x;
  const int* __restrict__ tmap = (const int*)(ws + WS_TMAP);
  const float2* __restrict__ part = (const float2*)(ws + WS_PART);
  float* __restrict__ probs = (float*)(ws + WS_PROBS);
  float* __restrict__ sums = (float*)(ws + WS_SUMS);
  int k = (slot < NSLOTS) ? tmap[slot] : -1;
  float bsum[NB];
  #pragma unroll
  for (int b=0;b<NB;b++){
    float pr = 0.0f;
    if (k >= 0){
      float2 amp = make_float2(0,0);
      #pragma unroll
      for (int sgq=0;sgq<NSGQ;sgq++){
        float2 v = part[(size_t)(b*NSGQ+sgq)*NSLOTS + slot];
        amp.x += v.x; amp.y += v.y;
      }
      pr = fmaf(amp.x, amp.x, amp.y*amp.y);
      probs[b*NSTATES + k] = pr;
    }
    bsum[b] = pr;
  }
  #pragma unroll
  for (int b=0;b<NB;b++){
    float v = bsum[b];
    for (int off=32; off>0; off>>=1) v += __shfl_down(v, off);
    if ((threadIdx.x & 63) == 0) atomicAdd(&sums[b], v);
  }
}

// ---------------- K4: out = probs_norm @ weight + bias (split-K, atomic) ----
// 403 blocks x 256 threads. thread: b = tid>>5, col4 = tid&31 (a float4 of
// output columns). Each block covers KS2=32 k-rows; weight read as float4
// (16 B/lane); probs scalar loads broadcast within half-wave (L1 hit).
// Ends with 4 atomicAdds/thread; 403 hits per address, hidden by stagger.
__global__ __launch_bounds__(256) void k_out(
    const float* __restrict__ wgt, const float* __restrict__ bias,
    const char* __restrict__ ws, float* __restrict__ out)
{
  const float* __restrict__ probs = (const float*)(ws + WS_PROBS);
  const float* __restrict__ sums = (const float*)(ws + WS_SUMS);
  int tid = threadIdx.x;
  int col4 = tid & 31, b = tid >> 5;
  int kb = blockIdx.x * KS2;
  int ke = min(NSTATES, kb + KS2);
  const float* __restrict__ pb = probs + (size_t)b * NSTATES;
  float4 acc = make_float4(0.f, 0.f, 0.f, 0.f);
  #pragma unroll 8
  for (int k = kb; k < ke; k++){
    float pf = pb[k];
    float4 wv = *(const float4*)(wgt + (size_t)k * OUTS + col4 * 4);
    acc.x = fmaf(pf, wv.x, acc.x);
    acc.y = fmaf(pf, wv.y, acc.y);
    acc.z = fmaf(pf, wv.z, acc.z);
    acc.w = fmaf(pf, wv.w, acc.w);
  }
  float inv = 1.0f / sums[b];
  int o = col4 * 4;
  float4 res;
  res.x = acc.x * inv; res.y = acc.y * inv;
  res.z = acc.z * inv; res.w = acc.w * inv;
  if (blockIdx.x == 0){
    res.x += bias[o+0]; res.y += bias[o+1];
    res.z += bias[o+2]; res.w += bias[o+3];
  }
  atomicAdd(&out[b*OUTS + o + 0], res.x);
  atomicAdd(&out[b*OUTS + o + 1], res.y);
  atomicAdd(&out[b*OUTS + o + 2], res.z);
  atomicAdd(&out[b*OUTS + o + 3], res.w);
}

// ---------------- launch ----------------
extern "C" void kernel_launch(void* const* d_in, const int* in_sizes, int n_in,
                              void* d_out, int out_size, void* d_ws, size_t ws_size,
                              hipStream_t stream) {
  const float* x    = (const float*)d_in[0];
  const float* th1  = (const float*)d_in[1];
  const float* th2  = (const float*)d_in[2];
  const float* mr   = (const float*)d_in[3];
  const float* mi   = (const float*)d_in[4];
  const float* wgt  = (const float*)d_in[5];
  const float* bias = (const float*)d_in[6];
  const int*   rows = (const int*)d_in[7];
  float* out = (float*)d_out;
  char* ws = (char*)d_ws;

  hipMemsetAsync(ws + WS_SUMS, 0, 32, stream);
  hipMemsetAsync(ws + WS_TMAP, 0xFF, TMAP_BYTES, stream);
  hipMemsetAsync(d_out, 0, (size_t)out_size * sizeof(float), stream);

  k_setup<<<NB + (NSTATES + 255)/256, 256, 0, stream>>>(x, th1, th2, mr, mi, rows, ws);
  k_main<<<NB*NSGQ*NTG, 256, 0, stream>>>(ws);
  k_reduce<<<(NSLOTS + 255)/256, 256, 0, stream>>>(ws);
  k_out<<<NSPLIT, 256, 0, stream>>>(wgt, bias, ws, out);
}

// Round 3
// 132.486 us; speedup vs baseline: 1.3783x; 1.3769x over previous
//
#include <hip/hip_runtime.h>
#include <math.h>

// ---------------- problem constants ----------------
#define NB 8          // batch
#define NM 16         // modes
#define NPH 8         // photons
#define NSTATES 12870 // C(16,8)
#define NSUB 256      // 2^NPH column subsets
#define OUTS 128
#define NTILES 824    // sum over classes of ceil(R/4)*ceil(C/4)
#define NSLOTS (NTILES*16) // 13184
#define NSGQ 8        // s-groups of 32 (partial-accumulation granularity)
#define SPH 16        // s per LDS phase (2 phases per s-group)
#define NTG 4         // tile groups
#define TILES_PER_TG 206
#define NSPLIT 128    // split-K blocks in output gemm
#define KS2 101       // k-rows per block (128*101 >= 12870)
#define NRBLK 52      // k_reduce blocks per batch (ceil(NSLOTS/256))

// ---------------- compile-time tables ----------------
struct Tables {
  int binom[17][9];
  unsigned char cls_masks[256]; // 8-bit masks sorted by (popcount, value)
  int cls_off[10];              // offsets into cls_masks per popcount
  int nt1[9], nt2[9];           // 4-tiles per dim per class
  int tile_off[10];
};

constexpr int cpopc(int x){ int c=0; while(x){ c += x & 1; x >>= 1; } return c; }

constexpr Tables make_tables(){
  Tables t{};
  for (int n=0;n<=16;n++)
    for (int k=0;k<=8;k++){
      if (k==0) t.binom[n][k]=1;
      else if (n==0) t.binom[n][k]=0;
      else t.binom[n][k]=t.binom[n-1][k-1]+t.binom[n-1][k];
    }
  int idx=0;
  for (int p=0;p<=8;p++){
    t.cls_off[p]=idx;
    for (int m=0;m<256;m++) if (cpopc(m)==p) t.cls_masks[idx++]=(unsigned char)m;
  }
  t.cls_off[9]=idx; // 256
  int toff=0;
  for (int c=0;c<=8;c++){
    int R=t.binom[8][c], C=t.binom[8][8-c];
    t.nt1[c]=(R+3)/4; t.nt2[c]=(C+3)/4;
    t.tile_off[c]=toff; toff += t.nt1[c]*t.nt2[c];
  }
  t.tile_off[9]=toff;
  return t;
}

constexpr Tables HTBL = make_tables();
static_assert(HTBL.tile_off[9]==NTILES, "tile count");
static_assert(HTBL.cls_off[9]==256, "mask count");
__device__ const Tables TBL = HTBL;

// next-pow2 shift for masks-per-level: C(8,p) = 1,8,28,56,70,56,28,8,1
__device__ const int LVL_SHIFT[9] = {0,3,5,6,7,6,5,3,0};

// ---------------- workspace layout (bytes) ----------------
// WS_V is dead after k_main  -> k_reduce writes per-block batch sums there.
// WS_PART is dead after k_reduce -> k_out writes gemm partials there.
#define WS_V      256                      // [NB][NSUB][NM] float2 = 262144 B
#define WS_BSUM   WS_V                     // [NB][NRBLK] float (overlay, 1664 B)
#define WS_TMAP   262400                   // NSLOTS ints = 52736 B (memset 0xFF)
#define WS_PROBS  315136                   // [NB][NSTATES] float = 411840 B
#define WS_PART   727040                   // [NB][NSGQ][NSLOTS] float2 = 6750208 B
#define WS_POUT   WS_PART                  // [NSPLIT][NB][OUTS] float (overlay, 512 KB)
#define TMAP_BYTES (NSLOTS*4)

// ---------------- complex helpers ----------------
__device__ __forceinline__ float2 cmul(float2 a, float2 b){
  return make_float2(fmaf(a.x,b.x,-(a.y*b.y)), fmaf(a.x,b.y, a.y*b.x));
}
__device__ __forceinline__ void cmac(float2& acc, float2 a, float2 b){
  acc.x = fmaf(a.x, b.x, acc.x); acc.x = fmaf(-a.y, b.y, acc.x);
  acc.y = fmaf(a.x, b.y, acc.y); acc.y = fmaf(a.y, b.x, acc.y);
}

// ---------------- K1: unitaries + V table + tile map ----------------
__global__ __launch_bounds__(256) void k_setup(
    const float* __restrict__ x, const float* __restrict__ th1,
    const float* __restrict__ th2, const float* __restrict__ mr,
    const float* __restrict__ mi, const int* __restrict__ rows, char* ws)
{
  int tid = threadIdx.x;
  if (blockIdx.x < NB) {
    int b = blockIdx.x;
    __shared__ float2 T1[NM][NM], T2[NM][NM], Am[NM][NM], Bm[NM][NM];
    __shared__ float2 EA[NM][NPH], Uin[NM][NPH], ex[NM];
    int r = tid >> 4, cc = tid & 15;
    {
      float sn, cs;
      sincosf(th1[r], &sn, &cs);
      float a = mr[0*256 + tid], bb = mi[0*256 + tid];   // M0[r][cc]
      T1[r][cc] = make_float2(cs*a - sn*bb, cs*bb + sn*a);
      sincosf(th2[r], &sn, &cs);
      float a2 = mr[2*256 + tid], b2 = mi[2*256 + tid];  // M2[r][cc]
      T2[r][cc] = make_float2(cs*a2 - sn*b2, cs*b2 + sn*a2);
    }
    __syncthreads();
    {
      float2 accA = make_float2(0,0), accB = make_float2(0,0);
      for (int m=0;m<NM;m++){
        float2 m1 = make_float2(mr[1*256 + r*16+m], mi[1*256 + r*16+m]);
        cmac(accA, m1, T1[m][cc]);
        float2 m3 = make_float2(mr[3*256 + r*16+m], mi[3*256 + r*16+m]);
        cmac(accB, m3, T2[m][cc]);
      }
      Am[r][cc] = accA; Bm[r][cc] = accB;
    }
    if (tid < NM){ float sn,cs; sincosf(x[b*NM+tid], &sn, &cs); ex[tid] = make_float2(cs, sn); }
    __syncthreads();
    if (tid < NM*NPH){ int m = tid >> 3, n = tid & 7; EA[m][n] = cmul(ex[m], Am[m][n]); }
    __syncthreads();
    if (tid < NM*NPH){
      int p = tid >> 3, n = tid & 7;
      float2 acc = make_float2(0,0);
      for (int m=0;m<NM;m++) cmac(acc, Bm[p][m], EA[m][n]);
      Uin[p][n] = acc;
    }
    __syncthreads();
    // V[s][m] = sum over set bits j of s of Uin[m][j];  thread tid == s
    float2* Vg = (float2*)(ws + WS_V);
    int s = tid;
    for (int m=0;m<NM;m++){
      float2 acc = make_float2(0,0);
      #pragma unroll
      for (int j=0;j<NPH;j++)
        if ((s>>j) & 1){ acc.x += Uin[m][j].x; acc.y += Uin[m][j].y; }
      Vg[b*(NSUB*NM) + s*NM + m] = acc;
    }
  } else {
    // tile map: state k -> (tile, slot)
    int k = (blockIdx.x - NB)*256 + tid;
    if (k < NSTATES){
      int t1=0, t2=0;
      #pragma unroll
      for (int i=0;i<NPH;i++){
        int rr = rows[k*NPH+i];
        if (rr < 8) t1 |= 1 << rr; else t2 |= 1 << (rr-8);
      }
      int c1 = __popc(t1);
      int rk1=0, cnt=0;
      #pragma unroll
      for (int bb=0;bb<8;bb++) if ((t1>>bb)&1){ cnt++; rk1 += TBL.binom[bb][cnt]; }
      int rk2=0; cnt=0;
      #pragma unroll
      for (int bb=0;bb<8;bb++) if ((t2>>bb)&1){ cnt++; rk2 += TBL.binom[bb][cnt]; }
      int tile = TBL.tile_off[c1] + (rk1>>2)*TBL.nt2[c1] + (rk2>>2);
      int slot = ((rk1&3)<<2) | (rk2&3);
      ((int*)(ws + WS_TMAP))[tile*16 + slot] = k;
    }
  }
}

// ---------------- K2: factorized Ryser main ----------------
__global__ __launch_bounds__(256) void k_main(char* ws)
{
  __shared__ float2 P1L[SPH][256];   // 32 KB
  __shared__ float2 P2L[SPH][256];   // 32 KB  (total exactly 64 KB)
  const float2* __restrict__ Vg = (const float2*)(ws + WS_V);
  float2* __restrict__ part = (float2*)(ws + WS_PART);
  int tid = threadIdx.x;
  int blk = blockIdx.x;
  int b = blk >> 5, rest = blk & 31, sgq = rest >> 2, tg = rest & 3;
  bool active = tid < TILES_PER_TG;
  int tile = tg + 4*tid;
  int t1v[4] = {0,0,0,0}, t2v[4] = {0,0,0,0};
  if (active){
    int c = 0;
    while (tile >= TBL.tile_off[c+1]) c++;
    int local = tile - TBL.tile_off[c];
    int n2 = TBL.nt2[c];
    int ti = local / n2, tj = local - ti*n2;
    int R = TBL.binom[8][c], C2 = TBL.binom[8][8-c];
    #pragma unroll
    for (int i=0;i<4;i++){ int r1 = ti*4+i; t1v[i] = (r1<R) ? (int)TBL.cls_masks[TBL.cls_off[c]+r1] : 0; }
    #pragma unroll
    for (int j=0;j<4;j++){ int r2 = tj*4+j; t2v[j] = (r2<C2) ? (int)TBL.cls_masks[TBL.cls_off[8-c]+r2] : 0; }
  }
  float2 acc[4][4] = {};
  for (int ph=0; ph<2; ph++){
    int sbase = sgq*32 + ph*SPH;
    // level-0 init (sign of Ryser folded into P1)
    if (tid < 2*SPH){
      int table = tid >> 4, s = tid & 15;
      float sg = 1.0f;
      if (table==0 && (__popc(sbase+s) & 1)) sg = -1.0f;
      (table ? P2L : P1L)[s][0] = make_float2(sg, 0.0f);
    }
    __syncthreads();
    // DP build: P[t] = P[t & (t-1)] * V[row(lowbit)]
    for (int p=1;p<=8;p++){
      int nm = TBL.cls_off[p+1]-TBL.cls_off[p];
      int sh = LVL_SHIFT[p];
      int tot = (2*SPH) << sh;
      for (int q=tid; q<tot; q+=256){
        int mi2 = q & ((1<<sh)-1);
        if (mi2 < nm){
          int ts = q >> sh; int s = ts & 15, table = ts >> 4;
          int t = (int)TBL.cls_masks[TBL.cls_off[p]+mi2];
          int par = t & (t-1);
          int row = (__ffs(t)-1) + table*8;
          float2 pv = (table ? P2L : P1L)[s][par];
          float2 vv = Vg[b*(NSUB*NM) + (sbase+s)*NM + row];
          (table ? P2L : P1L)[s][t] = cmul(pv, vv);
        }
      }
      __syncthreads();
    }
    // 4x4 register-tiled combine
    if (active){
      for (int s=0;s<SPH;s++){
        float2 av[4], bv[4];
        #pragma unroll
        for (int i=0;i<4;i++) av[i] = P1L[s][t1v[i]];
        #pragma unroll
        for (int j=0;j<4;j++) bv[j] = P2L[s][t2v[j]];
        #pragma unroll
        for (int i=0;i<4;i++)
          #pragma unroll
          for (int j=0;j<4;j++) cmac(acc[i][j], av[i], bv[j]);
      }
    }
    __syncthreads();
  }
  if (active){
    float2* dst = part + (size_t)(b*NSGQ + sgq)*NSLOTS + (size_t)tile*16;
    #pragma unroll
    for (int i=0;i<4;i++)
      #pragma unroll
      for (int j=0;j<4;j++) dst[i*4+j] = acc[i][j];
  }
}

// ---------------- K3: reduce partials -> probs + per-block batch sums ------
// grid (NRBLK, NB). No atomics: block sum -> bsum[b*NRBLK + blk].
__global__ __launch_bounds__(256) void k_reduce(char* ws)
{
  int tid = threadIdx.x;
  int slot = blockIdx.x*256 + tid;
  int b = blockIdx.y;
  const int* __restrict__ tmap = (const int*)(ws + WS_TMAP);
  const float2* __restrict__ part = (const float2*)(ws + WS_PART);
  float* __restrict__ probs = (float*)(ws + WS_PROBS);
  float* __restrict__ bsum = (float*)(ws + WS_BSUM);
  int k = (slot < NSLOTS) ? tmap[slot] : -1;
  float pr = 0.0f;
  if (k >= 0){
    float2 amp = make_float2(0,0);
    #pragma unroll
    for (int sgq=0;sgq<NSGQ;sgq++){
      float2 v = part[(size_t)(b*NSGQ+sgq)*NSLOTS + slot];
      amp.x += v.x; amp.y += v.y;
    }
    pr = fmaf(amp.x, amp.x, amp.y*amp.y);
    probs[b*NSTATES + k] = pr;
  }
  // block-level sum (wave shfl + LDS across the 4 waves)
  float v = pr;
  #pragma unroll
  for (int off=32; off>0; off>>=1) v += __shfl_down(v, off);
  __shared__ float wsum[4];
  if ((tid & 63) == 0) wsum[tid >> 6] = v;
  __syncthreads();
  if (tid == 0) bsum[b*NRBLK + blockIdx.x] = wsum[0]+wsum[1]+wsum[2]+wsum[3];
}

// ---------------- K4: unnormalized split-K gemm partials (no atomics) ------
// NSPLIT blocks x 256 threads. thread: b = tid>>5, col4 = tid&31.
// Writes pout[blk][b][col4*4..+3] as one float4.
__global__ __launch_bounds__(256) void k_out(
    const float* __restrict__ wgt, const char* __restrict__ ws, char* wsw)
{
  const float* __restrict__ probs = (const float*)(ws + WS_PROBS);
  float* __restrict__ pout = (float*)(wsw + WS_POUT);
  int tid = threadIdx.x;
  int col4 = tid & 31, b = tid >> 5;
  int kb = blockIdx.x * KS2;
  int ke = min(NSTATES, kb + KS2);
  const float* __restrict__ pb = probs + (size_t)b * NSTATES;
  float4 acc = make_float4(0.f, 0.f, 0.f, 0.f);
  #pragma unroll 8
  for (int k = kb; k < ke; k++){
    float pf = pb[k];
    float4 wv = *(const float4*)(wgt + (size_t)k * OUTS + col4 * 4);
    acc.x = fmaf(pf, wv.x, acc.x);
    acc.y = fmaf(pf, wv.y, acc.y);
    acc.z = fmaf(pf, wv.z, acc.z);
    acc.w = fmaf(pf, wv.w, acc.w);
  }
  *(float4*)(pout + (size_t)blockIdx.x * (NB*OUTS) + tid * 4) = acc;
}

// ---------------- K5: final reduce: out = (sum_s pout)/sums[b] + bias ------
// grid NB x 128 threads.
__global__ __launch_bounds__(128) void k_final(
    const float* __restrict__ bias, const char* __restrict__ ws,
    float* __restrict__ out)
{
  const float* __restrict__ pout = (const float*)(ws + WS_POUT);
  const float* __restrict__ bsum = (const float*)(ws + WS_BSUM);
  int o = threadIdx.x, b = blockIdx.x;
  float sum = 0.0f;
  #pragma unroll 4
  for (int j=0;j<NRBLK;j++) sum += bsum[b*NRBLK + j];
  float acc = 0.0f;
  #pragma unroll 8
  for (int s=0;s<NSPLIT;s++) acc += pout[(size_t)s*(NB*OUTS) + b*OUTS + o];
  out[b*OUTS + o] = acc / sum + bias[o];
}

// ---------------- launch ----------------
extern "C" void kernel_launch(void* const* d_in, const int* in_sizes, int n_in,
                              void* d_out, int out_size, void* d_ws, size_t ws_size,
                              hipStream_t stream) {
  const float* x    = (const float*)d_in[0];
  const float* th1  = (const float*)d_in[1];
  const float* th2  = (const float*)d_in[2];
  const float* mr   = (const float*)d_in[3];
  const float* mi   = (const float*)d_in[4];
  const float* wgt  = (const float*)d_in[5];
  const float* bias = (const float*)d_in[6];
  const int*   rows = (const int*)d_in[7];
  float* out = (float*)d_out;
  char* ws = (char*)d_ws;

  hipMemsetAsync(ws + WS_TMAP, 0xFF, TMAP_BYTES, stream);

  k_setup<<<NB + (NSTATES + 255)/256, 256, 0, stream>>>(x, th1, th2, mr, mi, rows, ws);
  k_main<<<NB*NSGQ*NTG, 256, 0, stream>>>(ws);
  k_reduce<<<dim3(NRBLK, NB), 256, 0, stream>>>(ws);
  k_out<<<NSPLIT, 256, 0, stream>>>(wgt, ws, ws);
  k_final<<<NB, 128, 0, stream>>>(bias, ws, out);
}